// Round 6
// baseline (109.386 us; speedup 1.0000x reference)
//
#include <hip/hip_runtime.h>

using bf16x8 = __attribute__((ext_vector_type(8))) short;
using f32x4  = __attribute__((ext_vector_type(4))) float;

#define B_SZ 8192
#define D_SZ 1024
#define H_SZ 128
#define C_SZ 256
#define T_SZ 16

#define SB __builtin_amdgcn_sched_barrier(0)

__device__ __forceinline__ unsigned short f2bf(float f) {
  unsigned int u = __float_as_uint(f);
  return (unsigned short)((u + 0x7fffu + ((u >> 16) & 1u)) >> 16);
}

// ------- transpose+cast: src[t][R][C] f32 -> dst[t][C][R] bf16 (k-major for MFMA) -------
__global__ __launch_bounds__(256) void transpose_cast_kernel(const float* __restrict__ src,
                                                             unsigned short* __restrict__ dst,
                                                             int R, int C, int cshift) {
  __shared__ float tile[32][257];
  const int t = blockIdx.y;
  const int r0 = blockIdx.x * 32;
  const float* s = src + ((size_t)t * R + r0) * C;
  const int n = 32 * C;
  for (int idx = threadIdx.x; idx < n; idx += 256)
    tile[idx >> cshift][idx & (C - 1)] = s[idx];
  __syncthreads();
  unsigned short* d = dst + (size_t)t * C * R + r0;
  for (int idx = threadIdx.x; idx < n; idx += 256) {
    int cc = idx >> 5, rr = idx & 31;
    d[(size_t)cc * R + rr] = f2bf(tile[rr][cc]);
  }
}

// ------ router + x-cast fused (float4): probs = softmax(x@Wr+br); xb = bf16(x) ------
__global__ __launch_bounds__(256) void router_cast_kernel(const float* __restrict__ x,
                                                          const float* __restrict__ Wr,
                                                          const float* __restrict__ br,
                                                          float* __restrict__ out0,
                                                          unsigned short* __restrict__ xb) {
  const int lane = threadIdx.x & 63;
  const int wid  = threadIdx.x >> 6;
  const int brow = blockIdx.x * 16 + wid * 4;
  float acc[4][16];
#pragma unroll
  for (int r = 0; r < 4; ++r)
#pragma unroll
    for (int tt = 0; tt < 16; ++tt) acc[r][tt] = 0.f;

#pragma unroll
  for (int it = 0; it < 4; ++it) {
    const int d0 = it * 256 + lane * 4;
    float wv[4][16];
#pragma unroll
    for (int dd = 0; dd < 4; ++dd) {
      const float4* w4 = (const float4*)(Wr + (size_t)(d0 + dd) * 16);
      float4 a = w4[0], b = w4[1], c = w4[2], d = w4[3];
      wv[dd][0]=a.x; wv[dd][1]=a.y; wv[dd][2]=a.z; wv[dd][3]=a.w;
      wv[dd][4]=b.x; wv[dd][5]=b.y; wv[dd][6]=b.z; wv[dd][7]=b.w;
      wv[dd][8]=c.x; wv[dd][9]=c.y; wv[dd][10]=c.z; wv[dd][11]=c.w;
      wv[dd][12]=d.x; wv[dd][13]=d.y; wv[dd][14]=d.z; wv[dd][15]=d.w;
    }
#pragma unroll
    for (int r = 0; r < 4; ++r) {
      const float4 xv = *(const float4*)(x + (size_t)(brow + r) * 1024 + d0);
      ushort4 o4;
      o4.x = f2bf(xv.x); o4.y = f2bf(xv.y); o4.z = f2bf(xv.z); o4.w = f2bf(xv.w);
      *(ushort4*)(xb + (size_t)(brow + r) * 1024 + d0) = o4;
      const float xs[4] = {xv.x, xv.y, xv.z, xv.w};
#pragma unroll
      for (int dd = 0; dd < 4; ++dd)
#pragma unroll
        for (int tt = 0; tt < 16; ++tt) acc[r][tt] += xs[dd] * wv[dd][tt];
    }
  }
#pragma unroll
  for (int off = 32; off >= 1; off >>= 1) {
#pragma unroll
    for (int r = 0; r < 4; ++r)
#pragma unroll
      for (int tt = 0; tt < 16; ++tt) acc[r][tt] += __shfl_xor(acc[r][tt], off);
  }
  if (lane == 0) {
#pragma unroll
    for (int r = 0; r < 4; ++r) {
      float v[16]; float m = -1e30f;
#pragma unroll
      for (int tt = 0; tt < 16; ++tt) { v[tt] = acc[r][tt] + br[tt]; m = fmaxf(m, v[tt]); }
      float ssum = 0.f;
#pragma unroll
      for (int tt = 0; tt < 16; ++tt) { v[tt] = __expf(v[tt] - m); ssum += v[tt]; }
      const float inv = 1.0f / ssum;
      float4* o = (float4*)(out0 + (size_t)(brow + r) * 16);
      o[0] = make_float4(v[0] * inv, v[1] * inv, v[2] * inv, v[3] * inv);
      o[1] = make_float4(v[4] * inv, v[5] * inv, v[6] * inv, v[7] * inv);
      o[2] = make_float4(v[8] * inv, v[9] * inv, v[10] * inv, v[11] * inv);
      o[3] = make_float4(v[12] * inv, v[13] * inv, v[14] * inv, v[15] * inv);
    }
  }
}

// ---------------- fused expert: per (t, 128-row tile) ----------------
// BM=128, 4 waves (2n x 2m), 64KB LDS -> 2 blocks/CU.
// kt schedule (retire-early): READ16->regs, lgkm0, barrier, STAGE(kt+2)->buf[cur]
// overlapped with 32 MFMA, vmcnt(8), barrier. Stage latency hides under MFMA.
// LDS: sX dbuf 2x16KB @0 | sW dbuf 2x16KB @32768 | sH [128][128]bf16 aliases sX.
#define SW_OFF 32768

__global__ __launch_bounds__(256, 2) void expert_kernel(
    const unsigned short* __restrict__ xb, const unsigned short* __restrict__ w1b,
    const unsigned short* __restrict__ w2b, const float* __restrict__ b1,
    const float* __restrict__ b2, const float* __restrict__ probs,
    float* __restrict__ out1) {
  __shared__ __align__(16) char smem[65536];
  const int tid  = threadIdx.x;
  const int lane = tid & 63;
  const int w    = tid >> 6;   // 0..3
  const int l16  = lane & 15;
  const int l4   = lane >> 4;  // 0..3

  // XCD-chunked bijective swizzle (1024 = 8 XCD * 128), t fastest within chunk
  const int bid = blockIdx.x;
  const int lid = (bid & 7) * 128 + (bid >> 3);
  const int t   = lid & 15;
  const int b0  = (lid >> 4) * 128;   // 64 row-tiles of 128

  // ---- staging precompute: 8 x 16B gload_lds per thread per kt ----
  const unsigned short* gp[8];
  unsigned int ldo[8];
#pragma unroll
  for (int it = 0; it < 8; ++it) {
    const unsigned int o = (unsigned int)w * 4096u + (unsigned int)(it & 3) * 1024u + (unsigned int)lane * 16u;
    const int row = (int)(o >> 7);
    const int cb  = (int)((o & 127u) ^ (((unsigned)row & 7u) << 4));
    gp[it]  = (it < 4) ? (xb + (size_t)(b0 + row) * 1024 + (cb >> 1))
                       : (w1b + (size_t)(t * 128 + row) * 1024 + (cb >> 1));
    ldo[it] = o;
  }

#define STAGE(curbuf, kt)                                                              \
  {                                                                                    \
    _Pragma("unroll")                                                                  \
    for (int it = 0; it < 8; ++it) {                                                   \
      const unsigned short* g = gp[it] + (kt) * 64;                                    \
      char* dd = smem + (it < 4 ? (curbuf) * 16384 + (int)ldo[it]                      \
                                : SW_OFF + (curbuf) * 16384 + (int)ldo[it]);           \
      __builtin_amdgcn_global_load_lds(                                                \
          (const __attribute__((address_space(1))) unsigned int*)g,                    \
          (__attribute__((address_space(3))) unsigned int*)dd, 16, 0, 0);              \
    }                                                                                  \
  }

  // fc1 wave grid: wn (2 n-halves of 64) x wm (2 m-halves of 64)
  const int wn = w & 1;
  const int wm = w >> 1;
  f32x4 acc1[4][4] = {};
  bf16x8 aw[2][4], bx[2][4];

  // READ16: whole kt's operands -> regs (retires buf[cur] at kt start)
#define READ16(curbuf)                                                                 \
  {                                                                                    \
    const int bx_base = (curbuf) * 16384;                                              \
    const int aw_base = SW_OFF + (curbuf) * 16384;                                     \
    _Pragma("unroll")                                                                  \
    for (int ks = 0; ks < 2; ++ks) {                                                   \
      const int cb = ks * 64 + l4 * 16;                                                \
      _Pragma("unroll")                                                                \
      for (int ni = 0; ni < 4; ++ni) {                                                 \
        const int row = wn * 64 + ni * 16 + l16;                                       \
        aw[ks][ni] = *(const bf16x8*)(smem + aw_base + (row << 7) + (cb ^ ((row & 7) << 4))); \
      }                                                                                \
      _Pragma("unroll")                                                                \
      for (int mi = 0; mi < 4; ++mi) {                                                 \
        const int row = wm * 64 + mi * 16 + l16;                                       \
        bx[ks][mi] = *(const bf16x8*)(smem + bx_base + (row << 7) + (cb ^ ((row & 7) << 4))); \
      }                                                                                \
    }                                                                                  \
  }

#define MFMA32                                                                         \
  {                                                                                    \
    __builtin_amdgcn_s_setprio(1);                                                     \
    _Pragma("unroll")                                                                  \
    for (int ks = 0; ks < 2; ++ks)                                                     \
      _Pragma("unroll")                                                                \
      for (int ni = 0; ni < 4; ++ni)                                                   \
        _Pragma("unroll")                                                              \
        for (int mi = 0; mi < 4; ++mi)                                                 \
          acc1[ni][mi] = __builtin_amdgcn_mfma_f32_16x16x32_bf16(aw[ks][ni], bx[ks][mi], acc1[ni][mi], 0, 0, 0); \
    __builtin_amdgcn_s_setprio(0);                                                     \
  }

  // prologue: 2-deep prefetch; wait buf0's 8 (kt1's 8 stay in flight)
  STAGE(0, 0);
  STAGE(1, 1);
  asm volatile("s_waitcnt vmcnt(8)" ::: "memory");
  SB; __builtin_amdgcn_s_barrier(); SB;

#pragma unroll
  for (int kt = 0; kt < 14; ++kt) {
    const int cur = kt & 1;
    READ16(cur);
    asm volatile("s_waitcnt lgkmcnt(0)" ::: "memory");  // reads in regs
    SB; __builtin_amdgcn_s_barrier(); SB;               // buf[cur] retired by ALL waves
    STAGE(cur, kt + 2);                                 // overlaps with MFMA below
    SB;
    MFMA32;
    asm volatile("s_waitcnt vmcnt(8)" ::: "memory");    // kt+1's 8 landed (kt+2's in flight)
    SB; __builtin_amdgcn_s_barrier(); SB;
  }
  // kt = 14 (cur=0): no staging
  READ16(0);
  asm volatile("s_waitcnt lgkmcnt(0)" ::: "memory");
  SB; __builtin_amdgcn_s_barrier(); SB;
  MFMA32;
  asm volatile("s_waitcnt vmcnt(0)" ::: "memory");      // kt15 landed
  SB; __builtin_amdgcn_s_barrier(); SB;
  // kt = 15 (cur=1)
  READ16(1);
  asm volatile("s_waitcnt lgkmcnt(0)" ::: "memory");
  SB; __builtin_amdgcn_s_barrier(); SB;                 // all reads done before aliased sH writes
  MFMA32;

  // fc1 epilogue: +b1, relu, cvt bf16, write hT -> sH[m][k=n] (swizzled, 8B stores)
#pragma unroll
  for (int ni = 0; ni < 4; ++ni) {
    const int n0 = wn * 64 + ni * 16 + l4 * 4;
    float bb[4];
#pragma unroll
    for (int r = 0; r < 4; ++r) bb[r] = b1[t * 128 + n0 + r];
#pragma unroll
    for (int mi = 0; mi < 4; ++mi) {
      const int m = wm * 64 + mi * 16 + l16;
      unsigned int pk[2];
#pragma unroll
      for (int h = 0; h < 2; ++h) {
        float v0 = fmaxf(acc1[ni][mi][2 * h + 0] + bb[2 * h + 0], 0.f);
        float v1 = fmaxf(acc1[ni][mi][2 * h + 1] + bb[2 * h + 1], 0.f);
        pk[h] = (unsigned int)f2bf(v0) | ((unsigned int)f2bf(v1) << 16);
      }
      const int byte = (m << 8) + ((n0 * 2) ^ ((m & 7) << 4));
      *(uint2*)(smem + byte) = make_uint2(pk[0], pk[1]);
    }
  }
  asm volatile("s_waitcnt lgkmcnt(0)" ::: "memory");  // ds_writes visible
  SB; __builtin_amdgcn_s_barrier(); SB;

  // fc2: wave grid wm2 (2 m-halves of 64) x wc (2 c-halves of 128)
  const int wm2 = w >> 1;
  const int wc  = w & 1;
  f32x4 acc2[4][8] = {};
  const unsigned short* w2t = w2b + (size_t)t * C_SZ * H_SZ;

#pragma unroll
  for (int ks = 0; ks < 4; ++ks) {
    const int cb = ks * 64 + l4 * 16;
    bf16x8 ah[4];
#pragma unroll
    for (int mi = 0; mi < 4; ++mi) {
      const int row = wm2 * 64 + mi * 16 + l16;
      ah[mi] = *(const bf16x8*)(smem + (row << 8) + (cb ^ ((row & 7) << 4)));
    }
#pragma unroll
    for (int ci = 0; ci < 8; ++ci) {
      const int c = wc * 128 + ci * 16 + l16;
      bf16x8 bw = *(const bf16x8*)(w2t + (size_t)c * 128 + ks * 32 + l4 * 8);
#pragma unroll
      for (int mi = 0; mi < 4; ++mi)
        acc2[mi][ci] = __builtin_amdgcn_mfma_f32_16x16x32_bf16(ah[mi], bw, acc2[mi][ci], 0, 0, 0);
    }
  }

  // fc2 epilogue: +b2, * probs, store f32
  const size_t outbase = (size_t)t * (size_t)(B_SZ * C_SZ);
#pragma unroll
  for (int mi = 0; mi < 4; ++mi) {
    const int m0 = wm2 * 64 + mi * 16 + l4 * 4;
    float pv[4];
#pragma unroll
    for (int r = 0; r < 4; ++r) pv[r] = probs[(size_t)(b0 + m0 + r) * 16 + t];
#pragma unroll
    for (int ci = 0; ci < 8; ++ci) {
      const int c = wc * 128 + ci * 16 + l16;
      const float bias = b2[t * 256 + c];
#pragma unroll
      for (int r = 0; r < 4; ++r)
        out1[outbase + (size_t)(b0 + m0 + r) * 256 + c] = (acc2[mi][ci][r] + bias) * pv[r];
    }
  }
}

extern "C" void kernel_launch(void* const* d_in, const int* in_sizes, int n_in,
                              void* d_out, int out_size, void* d_ws, size_t ws_size,
                              hipStream_t stream) {
  const float* x  = (const float*)d_in[0];
  const float* Wr = (const float*)d_in[1];
  const float* br = (const float*)d_in[2];
  const float* W1 = (const float*)d_in[3];
  const float* b1 = (const float*)d_in[4];
  const float* W2 = (const float*)d_in[5];
  const float* b2 = (const float*)d_in[6];
  float* out0 = (float*)d_out;                       // [B][T] probs
  float* out1 = out0 + (size_t)B_SZ * T_SZ;          // [T][B][C] preds

  char* ws = (char*)d_ws;
  unsigned short* xb  = (unsigned short*)ws;                                // 16 MiB [B][D]
  unsigned short* w1b = (unsigned short*)(ws + (size_t)16777216);           // 4 MiB  [T][H][D]
  unsigned short* w2b = (unsigned short*)(ws + (size_t)16777216 + 4194304); // 1 MiB  [T][C][H]

  router_cast_kernel<<<B_SZ / 16, 256, 0, stream>>>(x, Wr, br, out0, xb);
  transpose_cast_kernel<<<dim3(D_SZ / 32, T_SZ), 256, 0, stream>>>(W1, w1b, D_SZ, H_SZ, 7);
  transpose_cast_kernel<<<dim3(H_SZ / 32, T_SZ), 256, 0, stream>>>(W2, w2b, H_SZ, C_SZ, 8);
  expert_kernel<<<1024, 256, 0, stream>>>(xb, w1b, w2b, b1, b2, out0, out1);
}

// Round 7
// 108.168 us; speedup vs baseline: 1.0113x; 1.0113x over previous
//
#include <hip/hip_runtime.h>

using bf16x8 = __attribute__((ext_vector_type(8))) short;
using f32x4  = __attribute__((ext_vector_type(4))) float;

#define B_SZ 8192
#define D_SZ 1024
#define H_SZ 128
#define C_SZ 256
#define T_SZ 16

#define SB __builtin_amdgcn_sched_barrier(0)

__device__ __forceinline__ unsigned short f2bf(float f) {
  unsigned int u = __float_as_uint(f);
  return (unsigned short)((u + 0x7fffu + ((u >> 16) & 1u)) >> 16);
}

// ------- transpose+cast: src[t][R][C] f32 -> dst[t][C][R] bf16 (k-major for MFMA) -------
__global__ __launch_bounds__(256) void transpose_cast_kernel(const float* __restrict__ src,
                                                             unsigned short* __restrict__ dst,
                                                             int R, int C, int cshift) {
  __shared__ float tile[32][257];
  const int t = blockIdx.y;
  const int r0 = blockIdx.x * 32;
  const float* s = src + ((size_t)t * R + r0) * C;
  const int n = 32 * C;
  for (int idx = threadIdx.x; idx < n; idx += 256)
    tile[idx >> cshift][idx & (C - 1)] = s[idx];
  __syncthreads();
  unsigned short* d = dst + (size_t)t * C * R + r0;
  for (int idx = threadIdx.x; idx < n; idx += 256) {
    int cc = idx >> 5, rr = idx & 31;
    d[(size_t)cc * R + rr] = f2bf(tile[rr][cc]);
  }
}

// ------ router + x-cast fused (R4 scalar version): probs = softmax(x@Wr+br); xb = bf16(x) ------
__global__ __launch_bounds__(256) void router_cast_kernel(const float* __restrict__ x,
                                                          const float* __restrict__ Wr,
                                                          const float* __restrict__ br,
                                                          float* __restrict__ out0,
                                                          unsigned short* __restrict__ xb) {
  const int lane = threadIdx.x & 63;
  const int wid  = threadIdx.x >> 6;
  const int brow = blockIdx.x * 16 + wid * 4;
  float acc[4][16];
#pragma unroll
  for (int r = 0; r < 4; ++r)
#pragma unroll
    for (int tt = 0; tt < 16; ++tt) acc[r][tt] = 0.f;

  for (int it = 0; it < 16; ++it) {
    const int d = it * 64 + lane;
    const float4* w4 = (const float4*)(Wr + (size_t)d * 16);
    float4 wa = w4[0], wb = w4[1], wc = w4[2], wd = w4[3];
    const float wv[16] = {wa.x, wa.y, wa.z, wa.w, wb.x, wb.y, wb.z, wb.w,
                          wc.x, wc.y, wc.z, wc.w, wd.x, wd.y, wd.z, wd.w};
#pragma unroll
    for (int r = 0; r < 4; ++r) {
      const float xv = x[(size_t)(brow + r) * 1024 + d];
      xb[(size_t)(brow + r) * 1024 + d] = f2bf(xv);
#pragma unroll
      for (int tt = 0; tt < 16; ++tt) acc[r][tt] += xv * wv[tt];
    }
  }
#pragma unroll
  for (int off = 32; off >= 1; off >>= 1) {
#pragma unroll
    for (int r = 0; r < 4; ++r)
#pragma unroll
      for (int tt = 0; tt < 16; ++tt) acc[r][tt] += __shfl_xor(acc[r][tt], off);
  }
  if (lane == 0) {
#pragma unroll
    for (int r = 0; r < 4; ++r) {
      float v[16]; float m = -1e30f;
#pragma unroll
      for (int tt = 0; tt < 16; ++tt) { v[tt] = acc[r][tt] + br[tt]; m = fmaxf(m, v[tt]); }
      float ssum = 0.f;
#pragma unroll
      for (int tt = 0; tt < 16; ++tt) { v[tt] = __expf(v[tt] - m); ssum += v[tt]; }
      const float inv = 1.0f / ssum;
      float4* o = (float4*)(out0 + (size_t)(brow + r) * 16);
      o[0] = make_float4(v[0] * inv, v[1] * inv, v[2] * inv, v[3] * inv);
      o[1] = make_float4(v[4] * inv, v[5] * inv, v[6] * inv, v[7] * inv);
      o[2] = make_float4(v[8] * inv, v[9] * inv, v[10] * inv, v[11] * inv);
      o[3] = make_float4(v[12] * inv, v[13] * inv, v[14] * inv, v[15] * inv);
    }
  }
}

// ---------------- fused expert: per (t, 256-row tile), 8-phase-style schedule ----------------
// BM=256, BN=128, BK=64, 8 waves (4 wm x 2 wn), per-wave 64x64, 1 block/CU.
// Per kt: 4 phases, each {ds_read 2-6 b128, 1-2 gload_lds for kt+2, bar, setprio, 8 MFMA, setprio, bar}.
// 3-deep LDS rotation: stage target never aliases live reads; vmcnt(6) once per kt.
// LDS: sX 3x32KB @0 | sW 3x16KB @98304 | sH [256][128]bf16 (64KB) aliases sX buf1+buf2 (kt15 uses buf0).
#define SWB 98304
#define SH_O 32768

__global__ __launch_bounds__(512, 2) void expert_kernel(
    const unsigned short* __restrict__ xb, const unsigned short* __restrict__ w1b,
    const unsigned short* __restrict__ w2b, const float* __restrict__ b1,
    const float* __restrict__ b2, const float* __restrict__ probs,
    float* __restrict__ out1) {
  __shared__ __align__(16) char smem[147456];
  const int tid  = threadIdx.x;
  const int lane = tid & 63;
  const int w    = tid >> 6;   // 0..7
  const int l16  = lane & 15;
  const int l4   = lane >> 4;  // 0..3

  // XCD-chunked bijective swizzle (512 = 8 XCD * 64), t fastest within chunk
  const int bid = blockIdx.x;
  const int lid = (bid & 7) * 64 + (bid >> 3);
  const int t   = lid & 15;
  const int b0  = (lid >> 4) * 256;

  // ---- staging precompute: 6 x 16B gload_lds per thread per kt (512 thr) ----
  // it 0..3 -> sX (4x8KB), it 4..5 -> sW (2x8KB); linear LDS dest, inverse-swizzled source
  const unsigned short* gp[6];
  unsigned int ldo[6];
#pragma unroll
  for (int it = 0; it < 6; ++it) {
    const unsigned int o = (unsigned int)(it < 4 ? it : it - 4) * 8192u + (unsigned int)tid * 16u;
    const int row = (int)(o >> 7);
    const int cb  = (int)((o & 127u) ^ (((unsigned)row & 7u) << 4));
    gp[it]  = (it < 4) ? (xb + (size_t)(b0 + row) * 1024 + (cb >> 1))
                       : (w1b + (size_t)(t * 128 + row) * 1024 + (cb >> 1));
    ldo[it] = o;
  }

#define STAGE1(it_, nbuf_, kt_)                                                        \
  {                                                                                    \
    const unsigned short* g = gp[it_] + (kt_) * 64;                                    \
    char* dd = smem + ((it_) < 4 ? (nbuf_) * 32768 + (int)ldo[it_]                     \
                                 : SWB + (nbuf_) * 16384 + (int)ldo[it_]);             \
    __builtin_amdgcn_global_load_lds(                                                  \
        (const __attribute__((address_space(1))) unsigned int*)g,                      \
        (__attribute__((address_space(3))) unsigned int*)dd, 16, 0, 0);                \
  }

  // fc1 wave grid: wm (4 m-quads of 64) x wn (2 n-halves of 64)
  const int wn = w & 1;
  const int wm = w >> 1;
  f32x4 acc1[4][4] = {};
  bf16x8 aw[2][4], bx[2][4];

#define RD_AW(buf_, ks_)                                                               \
  {                                                                                    \
    const int cb = (ks_) * 64 + l4 * 16;                                               \
    _Pragma("unroll")                                                                  \
    for (int ni = 0; ni < 4; ++ni) {                                                   \
      const int row = wn * 64 + ni * 16 + l16;                                         \
      aw[ks_][ni] = *(const bf16x8*)(smem + SWB + (buf_) * 16384 + (row << 7) + (cb ^ ((row & 7) << 4))); \
    }                                                                                  \
  }
#define RD_BX(buf_, ks_, mi_)                                                          \
  {                                                                                    \
    const int cb = (ks_) * 64 + l4 * 16;                                               \
    const int row = wm * 64 + (mi_) * 16 + l16;                                        \
    bx[ks_][mi_] = *(const bf16x8*)(smem + (buf_) * 32768 + (row << 7) + (cb ^ ((row & 7) << 4))); \
  }
#define MFMA8(ks_, j_)                                                                 \
  {                                                                                    \
    __builtin_amdgcn_s_setprio(1);                                                     \
    _Pragma("unroll")                                                                  \
    for (int ni = 0; ni < 4; ++ni) {                                                   \
      acc1[ni][2*(j_)]   = __builtin_amdgcn_mfma_f32_16x16x32_bf16(aw[ks_][ni], bx[ks_][2*(j_)],   acc1[ni][2*(j_)],   0, 0, 0); \
      acc1[ni][2*(j_)+1] = __builtin_amdgcn_mfma_f32_16x16x32_bf16(aw[ks_][ni], bx[ks_][2*(j_)+1], acc1[ni][2*(j_)+1], 0, 0, 0); \
    }                                                                                  \
    __builtin_amdgcn_s_setprio(0);                                                     \
  }
#define BAR SB; __builtin_amdgcn_s_barrier(); SB

  // prologue: stage kt0 -> buf0, kt1 -> buf1; wait buf0's 6 (buf1's stay in flight)
#pragma unroll
  for (int it = 0; it < 6; ++it) STAGE1(it, 0, 0);
#pragma unroll
  for (int it = 0; it < 6; ++it) STAGE1(it, 1, 1);
  asm volatile("s_waitcnt vmcnt(6)" ::: "memory");
  BAR;

  int buf = 0, nbuf = 2;
  for (int kt = 0; kt < 16; ++kt) {
    const bool st = (kt < 14);
    // P0: 6 reads | 2 stage | 8 MFMA
    RD_AW(buf, 0); RD_BX(buf, 0, 0); RD_BX(buf, 0, 1);
    if (st) { STAGE1(0, nbuf, kt + 2); STAGE1(1, nbuf, kt + 2); }
    BAR;
    MFMA8(0, 0);
    BAR;
    // P1: 2 reads | 1 stage | 8 MFMA
    RD_BX(buf, 0, 2); RD_BX(buf, 0, 3);
    if (st) STAGE1(2, nbuf, kt + 2);
    BAR;
    MFMA8(0, 1);
    BAR;
    // P2: 6 reads | 2 stage | 8 MFMA
    RD_AW(buf, 1); RD_BX(buf, 1, 0); RD_BX(buf, 1, 1);
    if (st) { STAGE1(3, nbuf, kt + 2); STAGE1(4, nbuf, kt + 2); }
    BAR;
    MFMA8(1, 0);
    BAR;
    // P3: 2 reads | 1 stage | 8 MFMA | end-of-kt counted wait
    RD_BX(buf, 1, 2); RD_BX(buf, 1, 3);
    if (st) STAGE1(5, nbuf, kt + 2);
    BAR;
    MFMA8(1, 1);
    if (kt <= 13)      { asm volatile("s_waitcnt vmcnt(6)" ::: "memory"); }
    else if (kt == 14) { asm volatile("s_waitcnt vmcnt(0)" ::: "memory"); }
    BAR;
    buf  = (buf == 2)  ? 0 : buf + 1;
    nbuf = (nbuf == 2) ? 0 : nbuf + 1;
  }

  // fc1 epilogue: +b1, relu, cvt bf16, write hT -> sH[m][k=n] (swizzled, 8B stores)
#pragma unroll
  for (int ni = 0; ni < 4; ++ni) {
    const int n0 = wn * 64 + ni * 16 + l4 * 4;
    float bb[4];
#pragma unroll
    for (int r = 0; r < 4; ++r) bb[r] = b1[t * 128 + n0 + r];
#pragma unroll
    for (int mi = 0; mi < 4; ++mi) {
      const int m = wm * 64 + mi * 16 + l16;
      unsigned int pk[2];
#pragma unroll
      for (int h = 0; h < 2; ++h) {
        float v0 = fmaxf(acc1[ni][mi][2 * h + 0] + bb[2 * h + 0], 0.f);
        float v1 = fmaxf(acc1[ni][mi][2 * h + 1] + bb[2 * h + 1], 0.f);
        pk[h] = (unsigned int)f2bf(v0) | ((unsigned int)f2bf(v1) << 16);
      }
      const int byte = (m << 8) + ((n0 * 2) ^ ((m & 7) << 4));
      *(uint2*)(smem + SH_O + byte) = make_uint2(pk[0], pk[1]);
    }
  }
  asm volatile("s_waitcnt lgkmcnt(0)" ::: "memory");  // ds_writes visible
  BAR;

  // fc2: wave grid wm2 (4 m-quads of 64) x wc (2 c-halves of 128)
  const int wm2 = w >> 1;
  const int wc  = w & 1;
  f32x4 acc2[4][8] = {};
  const unsigned short* w2t = w2b + (size_t)t * C_SZ * H_SZ;

#pragma unroll
  for (int ks = 0; ks < 4; ++ks) {
    const int cb = ks * 64 + l4 * 16;
    bf16x8 ah[4];
#pragma unroll
    for (int mi = 0; mi < 4; ++mi) {
      const int row = wm2 * 64 + mi * 16 + l16;
      ah[mi] = *(const bf16x8*)(smem + SH_O + (row << 8) + (cb ^ ((row & 7) << 4)));
    }
#pragma unroll
    for (int ci = 0; ci < 8; ++ci) {
      const int c = wc * 128 + ci * 16 + l16;
      bf16x8 bw = *(const bf16x8*)(w2t + (size_t)c * 128 + ks * 32 + l4 * 8);
#pragma unroll
      for (int mi = 0; mi < 4; ++mi)
        acc2[mi][ci] = __builtin_amdgcn_mfma_f32_16x16x32_bf16(ah[mi], bw, acc2[mi][ci], 0, 0, 0);
    }
  }

  // fc2 epilogue: +b2, * probs, store f32
  const size_t outbase = (size_t)t * (size_t)(B_SZ * C_SZ);
#pragma unroll
  for (int mi = 0; mi < 4; ++mi) {
    const int m0 = wm2 * 64 + mi * 16 + l4 * 4;
    float pv[4];
#pragma unroll
    for (int r = 0; r < 4; ++r) pv[r] = probs[(size_t)(b0 + m0 + r) * 16 + t];
#pragma unroll
    for (int ci = 0; ci < 8; ++ci) {
      const int c = wc * 128 + ci * 16 + l16;
      const float bias = b2[t * 256 + c];
#pragma unroll
      for (int r = 0; r < 4; ++r)
        out1[outbase + (size_t)(b0 + m0 + r) * 256 + c] = (acc2[mi][ci][r] + bias) * pv[r];
    }
  }
}

extern "C" void kernel_launch(void* const* d_in, const int* in_sizes, int n_in,
                              void* d_out, int out_size, void* d_ws, size_t ws_size,
                              hipStream_t stream) {
  const float* x  = (const float*)d_in[0];
  const float* Wr = (const float*)d_in[1];
  const float* br = (const float*)d_in[2];
  const float* W1 = (const float*)d_in[3];
  const float* b1 = (const float*)d_in[4];
  const float* W2 = (const float*)d_in[5];
  const float* b2 = (const float*)d_in[6];
  float* out0 = (float*)d_out;                       // [B][T] probs
  float* out1 = out0 + (size_t)B_SZ * T_SZ;          // [T][B][C] preds

  char* ws = (char*)d_ws;
  unsigned short* xb  = (unsigned short*)ws;                                // 16 MiB [B][D]
  unsigned short* w1b = (unsigned short*)(ws + (size_t)16777216);           // 4 MiB  [T][H][D]
  unsigned short* w2b = (unsigned short*)(ws + (size_t)16777216 + 4194304); // 1 MiB  [T][C][H]

  router_cast_kernel<<<B_SZ / 16, 256, 0, stream>>>(x, Wr, br, out0, xb);
  transpose_cast_kernel<<<dim3(D_SZ / 32, T_SZ), 256, 0, stream>>>(W1, w1b, D_SZ, H_SZ, 7);
  transpose_cast_kernel<<<dim3(H_SZ / 32, T_SZ), 256, 0, stream>>>(W2, w2b, H_SZ, C_SZ, 8);
  expert_kernel<<<512, 512, 0, stream>>>(xb, w1b, w2b, b1, b2, out0, out1);
}